// Round 1
// baseline (1246.941 us; speedup 1.0000x reference)
//
#include <hip/hip_runtime.h>
#include <hip/hip_bf16.h>
#include <math.h>

// Problem constants (img 2048x2048, strides 4..64, 3 anchors/loc)
#define K_TOP 1000
#define NLEV  5
#define NSEL  5000          // 5 * 1000 candidates
#define NSLOT 5120          // 5 * 1024 slots (1024 stride per level)
#define ROWW  80            // u64 words per NMS mask row (5120 bits)
#define ATOT  1047552
#define BBOX_CLIP_F 4.135166556742356f

// ws layout in u32 units
#define HISTA   0          // 5*2048
#define HISTB   10240
#define HISTC   20480
#define INFO1   30720      // 5*4: [prefix, aboveTotal, need, pad]
#define INFO2   30740
#define INFO3   30760
#define CANDCNT 30780      // 5
#define EQCNT   30785      // 5
#define MAXC    30790      // 1 (float bits)
#define KEPT    30791      // 1
#define CANDO   30800      // 5*1024 per-level local indices
#define EQO     35920      // 5*2048
#define KEYSO   46160      // u64[8192] -> 16384 u32 (8B aligned: 46160*4%8==0)
#define SORTCP  62544      // u32[5120] sorted concat-positions
#define BOXA    67664      // f32[5120][4] clipped boxes per slot
#define VALIDA  88144      // u32[5120]
#define NBSO    93264      // f32[5120][4] offset boxes, sorted order
#define AREAS   113744     // f32[5120]
#define VALS    118864     // u32[5120] valid in sorted order
#define ORDERED 123984     // u32[1024] kept sorted-positions
#define MASKO   125008     // u64[5000*80]  (125008*4 % 8 == 0)

__device__ __forceinline__ int loff(int l){
  return (l==0)?0:(l==1)?786432:(l==2)?983040:(l==3)?1032192:1044480;
}
__device__ __forceinline__ int lsize(int l){
  return (l==0)?786432:(l==1)?196608:(l==2)?49152:(l==3)?12288:3072;
}
// monotonic uint32 key: larger float <-> larger key
__device__ __forceinline__ unsigned fmono(float x){
  unsigned b=__float_as_uint(x);
  return (b&0x80000000u)? ~b : (b|0x80000000u);
}

template<typename T>
__device__ void bitonic_sort(T* sk, int n, int tid, int nth){
  for (int size=2; size<=n; size<<=1){
    for (int stride=size>>1; stride>0; stride>>=1){
      __syncthreads();
      for (int p=tid; p<(n>>1); p+=nth){
        int lo = ((p/stride)*stride<<1) + (p%stride);
        int hi = lo+stride;
        bool asc = ((lo & size)==0);
        T a=sk[lo], b=sk[hi];
        if ((a>b)==asc){ sk[lo]=b; sk[hi]=a; }
      }
    }
  }
  __syncthreads();
}

__global__ void k_init(unsigned* ws32){
  int t=blockIdx.x*blockDim.x+threadIdx.x;
  if (t<30800) ws32[t]=0u;
}

// histogram passes over monotonic objectness key: pass1 bits31..21, pass2 20..10 (given b1), pass3 9..0 (given b1b2)
__global__ void k_hist(const float* __restrict__ obj, unsigned* ws32, int pass){
  int l = blockIdx.y;
  int n = lsize(l), off = loff(l);
  int nbins = (pass==3)?1024:2048;
  unsigned* hist = ws32 + ((pass==1)?HISTA:(pass==2)?HISTB:HISTC) + l*((pass==3)?1024:2048);
  const unsigned* infoPrev = ws32 + ((pass==2)?INFO1:INFO2);
  __shared__ unsigned h[2048];
  for (int t=threadIdx.x; t<nbins; t+=blockDim.x) h[t]=0u;
  __syncthreads();
  unsigned pref = (pass>1)? infoPrev[l*4] : 0u;
  for (int i = blockIdx.x*blockDim.x + threadIdx.x; i<n; i += gridDim.x*blockDim.x){
    unsigned key = fmono(obj[off+i]);
    int bin = -1;
    if (pass==1) bin = key>>21;
    else if (pass==2){ if ((key>>21)==pref) bin=(key>>10)&0x7FF; }
    else { if ((key>>10)==pref) bin = key & 0x3FF; }
    if (bin>=0) atomicAdd(&h[bin],1u);
  }
  __syncthreads();
  for (int t=threadIdx.x; t<nbins; t+=blockDim.x){
    unsigned v=h[t];
    if (v) atomicAdd(&hist[t], v);
  }
}

// descending cumulative scan over hist to find the bin containing the k-th element
__global__ void k_scan(unsigned* ws32, int pass){
  int l = blockIdx.x;
  int tid = threadIdx.x; // 256
  int nbins = (pass==3)?1024:2048;
  const unsigned* hist = ws32 + ((pass==1)?HISTA:(pass==2)?HISTB:HISTC) + l*((pass==3)?1024:2048);
  unsigned* infoOut = ws32 + ((pass==1)?INFO1:(pass==2)?INFO2:INFO3);
  const unsigned* infoPrev = ws32 + ((pass==2)?INFO1:INFO2);
  __shared__ unsigned psum[256];
  __shared__ unsigned sNeed, sAbove, sPrefix;
  if (tid==0){
    if (pass==1){ sNeed=K_TOP; sAbove=0u; sPrefix=0u; }
    else { sNeed=infoPrev[l*4+2]; sAbove=infoPrev[l*4+1]; sPrefix=infoPrev[l*4+0]; }
  }
  __syncthreads();
  int per = nbins/256;
  unsigned local=0;
  for (int r=tid*per; r<tid*per+per; r++) local += hist[nbins-1-r];
  psum[tid]=local; __syncthreads();
  for (int s=1;s<256;s<<=1){
    unsigned v = (tid>=s)? psum[tid-s] : 0u;
    __syncthreads();
    psum[tid]+=v;
    __syncthreads();
  }
  unsigned excl = (tid==0)?0u:psum[tid-1];
  unsigned need = sNeed;
  if (excl < need && psum[tid] >= need){
    unsigned cum = excl;
    for (int r=tid*per; r<tid*per+per; r++){
      unsigned hv = hist[nbins-1-r];
      if (cum + hv >= need){
        unsigned bin = (unsigned)(nbins-1-r);
        unsigned prefix;
        if (pass==1) prefix=bin;
        else if (pass==2) prefix=(sPrefix<<11)|bin;
        else prefix=(sPrefix<<10)|bin;
        infoOut[l*4+0]=prefix;
        infoOut[l*4+1]=sAbove + cum;     // count strictly greater
        infoOut[l*4+2]=need - cum;       // still needed from this bin
        break;
      }
      cum += hv;
    }
  }
}

__global__ void k_select(const float* __restrict__ obj, unsigned* ws32){
  unsigned* cand = ws32 + CANDO;
  unsigned* eq = ws32 + EQO;
  for (int g = blockIdx.x*blockDim.x + threadIdx.x; g<ATOT; g += gridDim.x*blockDim.x){
    int l = (g<786432)?0:(g<983040)?1:(g<1032192)?2:(g<1044480)?3:4;
    unsigned key = fmono(obj[g]);
    unsigned kstar = ws32[INFO3 + l*4];
    if (key > kstar){
      unsigned p = atomicAdd(&ws32[CANDCNT+l],1u);
      if (p<1024u) cand[l*1024+p] = (unsigned)(g - loff(l));
    } else if (key == kstar){
      unsigned p = atomicAdd(&ws32[EQCNT+l],1u);
      if (p<2048u) eq[l*2048+p] = (unsigned)(g - loff(l));
    }
  }
}

// among the elements equal to the k-th key, take the lowest indices (lax.top_k tie rule)
__global__ void k_eqfix(unsigned* ws32){
  int l = blockIdx.x;
  __shared__ unsigned s[2048];
  unsigned cnt = ws32[EQCNT+l]; if (cnt>2048u) cnt=2048u;
  unsigned base = ws32[CANDCNT+l];
  unsigned need = K_TOP - base;
  for (int t=threadIdx.x; t<2048; t+=blockDim.x)
    s[t] = (t<(int)cnt)? ws32[EQO + l*2048 + t] : 0xFFFFFFFFu;
  __syncthreads();
  bitonic_sort<unsigned>(s, 2048, threadIdx.x, blockDim.x);
  for (int t=threadIdx.x; t<(int)need; t+=blockDim.x)
    ws32[CANDO + l*1024 + base + t] = s[t];
}

// sort each level's 1000 selected by (objectness desc, idx asc) -> top_k concat order
__global__ void k_sortlvl(const float* __restrict__ obj, unsigned* ws32){
  int l = blockIdx.x;
  __shared__ unsigned long long k[1024];
  int off = loff(l);
  for (int t=threadIdx.x; t<1024; t+=blockDim.x){
    if (t<K_TOP){
      unsigned idx = ws32[CANDO + l*1024 + t];
      unsigned m = ~fmono(obj[off+idx]);
      k[t] = ((unsigned long long)m<<20) | idx;
    } else k[t] = ~0ULL;
  }
  __syncthreads();
  bitonic_sort<unsigned long long>(k, 1024, threadIdx.x, blockDim.x);
  for (int t=threadIdx.x; t<K_TOP; t+=blockDim.x)
    ws32[CANDO + l*1024 + t] = (unsigned)(k[t] & 0xFFFFFu);
}

// decode + clip + valid + sigmoid score key; replicate fp32 semantics (no FMA contraction)
__global__ void k_decode(const float* __restrict__ obj, const float* __restrict__ deltas,
                         const float* __restrict__ anchors, unsigned* ws32){
  int s = blockIdx.x*blockDim.x + threadIdx.x;  // 5*1024
  int l = s>>10, j = s&1023;
  unsigned long long key = ~0ULL;
  unsigned long long* keys = (unsigned long long*)(ws32+KEYSO);
  if (j < K_TOP){
    unsigned idx = ws32[CANDO + s];
    int g = loff(l) + (int)idx;
    float o = obj[g];
    const float* dd = deltas + 4*(size_t)g;
    const float* aa = anchors + 4*(size_t)g;
    float dx=dd[0], dy=dd[1], dw=dd[2], dh=dd[3];
    float a0=aa[0], a1=aa[1], a2=aa[2], a3=aa[3];
    float w = __fsub_rn(a2,a0), h = __fsub_rn(a3,a1);
    float cx = __fadd_rn(a0, __fmul_rn(0.5f,w));
    float cy = __fadd_rn(a1, __fmul_rn(0.5f,h));
    float dwc = fminf(dw, BBOX_CLIP_F);
    float dhc = fminf(dh, BBOX_CLIP_F);
    float pcx = __fadd_rn(__fmul_rn(dx,w), cx);
    float pcy = __fadd_rn(__fmul_rn(dy,h), cy);
    float pw = __fmul_rn((float)exp((double)dwc), w);
    float ph = __fmul_rn((float)exp((double)dhc), h);
    float x1 = __fsub_rn(pcx, __fmul_rn(0.5f,pw));
    float y1 = __fsub_rn(pcy, __fmul_rn(0.5f,ph));
    float x2 = __fadd_rn(pcx, __fmul_rn(0.5f,pw));
    float y2 = __fadd_rn(pcy, __fmul_rn(0.5f,ph));
    float x1c=fminf(fmaxf(x1,0.0f),2048.0f);
    float y1c=fminf(fmaxf(y1,0.0f),2048.0f);
    float x2c=fminf(fmaxf(x2,0.0f),2048.0f);
    float y2c=fminf(fmaxf(y2,0.0f),2048.0f);
    bool valid = (__fsub_rn(x2c,x1c)>=0.001f) && (__fsub_rn(y2c,y1c)>=0.001f);
    float* bx = (float*)(ws32+BOXA) + 4*s;
    bx[0]=x1c; bx[1]=y1c; bx[2]=x2c; bx[3]=y2c;
    ws32[VALIDA+s] = valid?1u:0u;
    double sg = 1.0/(1.0+exp(-(double)o));
    float sc = (float)sg;
    if (sc < 0.0f) valid = false;   // score >= SCORE_THRESH (always true for sigmoid)
    float masked = valid? sc : -1.0f;
    unsigned sm = ~fmono(masked);
    int cp = l*K_TOP + j;           // concat position
    key = ((unsigned long long)sm<<13) | (unsigned)cp;
    float mx = fmaxf(fmaxf(x1c,y1c),fmaxf(x2c,y2c));
    atomicMax(&ws32[MAXC], __float_as_uint(mx));
  }
  keys[s]=key;
}

// global stable sort: (masked score desc, concat position asc)
__global__ void k_sortglob(unsigned* ws32){
  __shared__ unsigned long long sk[8192];   // 64 KiB
  const unsigned long long* keys = (const unsigned long long*)(ws32+KEYSO);
  for (int t=threadIdx.x; t<8192; t+=blockDim.x)
    sk[t] = (t<NSLOT)? keys[t] : ~0ULL;
  __syncthreads();
  bitonic_sort<unsigned long long>(sk, 8192, threadIdx.x, blockDim.x);
  for (int t=threadIdx.x; t<NSEL; t+=blockDim.x)
    ws32[SORTCP+t] = (unsigned)(sk[t] & 0x1FFFULL);
}

// gather sorted candidates, apply level offsets (exactly as reference), areas
__global__ void k_prep(unsigned* ws32){
  int i = blockIdx.x*blockDim.x + threadIdx.x;
  if (i>=NSEL) return;
  unsigned cp = ws32[SORTCP+i];
  int l = cp/1000, j = cp - l*1000;
  int s = (l<<10)|j;
  const float* bx = (const float*)(ws32+BOXA) + 4*s;
  float mc = __uint_as_float(ws32[MAXC]);
  float offv = __fmul_rn((float)l, __fadd_rn(mc,1.0f));
  float n0=__fadd_rn(bx[0],offv), n1=__fadd_rn(bx[1],offv);
  float n2=__fadd_rn(bx[2],offv), n3=__fadd_rn(bx[3],offv);
  float* nb = (float*)(ws32+NBSO) + 4*i;
  nb[0]=n0; nb[1]=n1; nb[2]=n2; nb[3]=n3;
  ((float*)(ws32+AREAS))[i] = __fmul_rn(__fsub_rn(n2,n0), __fsub_rn(n3,n1));
  ws32[VALS+i] = ws32[VALIDA+s];
}

// suppression bitmask rows: bit j of row i => IoU(i,j) > 0.7 (reference arithmetic)
__global__ void k_mask(unsigned* ws32){
  int t = blockIdx.x*blockDim.x + threadIdx.x;
  if (t >= NSEL*ROWW) return;
  int i = t/ROWW, w = t - i*ROWW;
  const float* nbS = (const float*)(ws32+NBSO);
  const float* areaS = (const float*)(ws32+AREAS);
  unsigned long long* mask = (unsigned long long*)(ws32+MASKO);
  float bx1=nbS[4*i], by1=nbS[4*i+1], bx2=nbS[4*i+2], by2=nbS[4*i+3];
  float ai=areaS[i];
  unsigned long long word=0ULL;
  int jbase=w*64;
  #pragma unroll 4
  for (int bj=0; bj<64; bj++){
    int j=jbase+bj;
    if (j>=NSEL) break;
    float iw = fmaxf(__fsub_rn(fminf(nbS[4*j+2],bx2), fmaxf(nbS[4*j+0],bx1)),0.0f);
    float ih = fmaxf(__fsub_rn(fminf(nbS[4*j+3],by2), fmaxf(nbS[4*j+1],by1)),0.0f);
    float inter=__fmul_rn(iw,ih);
    float iou=__fdiv_rn(inter, __fsub_rn(__fadd_rn(areaS[j],ai),inter));
    if (iou>0.7f) word |= (1ULL<<bj);
  }
  mask[(size_t)i*ROWW + w]=word;
}

__device__ __forceinline__ unsigned long long shfl64(unsigned long long v, int lane){
  int lo = __shfl((int)(unsigned)(v & 0xFFFFFFFFULL), lane, 64);
  int hi = __shfl((int)(unsigned)(v >> 32), lane, 64);
  return ((unsigned long long)(unsigned)hi<<32) | (unsigned)lo;
}

// single-wave sequential greedy scan over the bitmask (chunked prefetch)
__global__ void __launch_bounds__(64) k_nms(unsigned* ws32){
  const unsigned long long* mask = (const unsigned long long*)(ws32+MASKO);
  int lane = threadIdx.x;
  unsigned long long r0=0ULL, r1=0ULL;  // lane owns word lane (r0) and 64+lane (r1, lanes<16)
  int rank=0;
  const int CH=8;                        // 5000 % 8 == 0
  unsigned long long mlo[CH], mhi[CH];
  for (int base=0; base<NSEL; base+=CH){
    #pragma unroll
    for (int c=0;c<CH;c++){
      mlo[c] = mask[(size_t)(base+c)*ROWW + lane];
      mhi[c] = (lane<16)? mask[(size_t)(base+c)*ROWW + 64 + lane] : 0ULL;
    }
    #pragma unroll
    for (int c=0;c<CH;c++){
      int i = base+c;
      int w = i>>6, b = i&63;
      unsigned long long w0 = shfl64(r0, w&63);
      unsigned long long w1 = shfl64(r1, (w>=64)?(w-64):0);
      unsigned long long word = (w<64)? w0 : w1;
      bool sup = (word>>b)&1ULL;
      bool keep = (ws32[VALS+i]!=0u) && !sup;
      if (keep){
        r0 |= mlo[c];
        r1 |= mhi[c];
        if (lane==0 && rank<K_TOP) ws32[ORDERED+rank]=(unsigned)i;
        rank++;
      }
    }
  }
  if (lane==0) ws32[KEPT] = (unsigned)((rank>K_TOP)?K_TOP:rank);
}

__global__ void k_out(const unsigned* __restrict__ ws32, float* __restrict__ out){
  int r = blockIdx.x*blockDim.x + threadIdx.x;
  if (r>=K_TOP) return;
  unsigned cnt = ws32[KEPT];
  float4 v = make_float4(0.f,0.f,0.f,0.f);
  if (r < (int)cnt){
    unsigned i = ws32[ORDERED + r];
    unsigned cp = ws32[SORTCP + i];
    int l = cp/1000, j = cp - l*1000;
    int s = (l<<10)|j;
    const float* b = (const float*)(ws32+BOXA) + 4*s;
    v = make_float4(b[0],b[1],b[2],b[3]);
  }
  ((float4*)out)[r] = v;
}

extern "C" void kernel_launch(void* const* d_in, const int* in_sizes, int n_in,
                              void* d_out, int out_size, void* d_ws, size_t ws_size,
                              hipStream_t stream){
  const float* obj     = (const float*)d_in[0];
  const float* deltas  = (const float*)d_in[1];
  const float* anchors = (const float*)d_in[2];
  unsigned* ws32 = (unsigned*)d_ws;
  float* out = (float*)d_out;
  (void)in_sizes; (void)n_in; (void)out_size; (void)ws_size;

  hipLaunchKernelGGL(k_init,     dim3(128),      dim3(256), 0, stream, ws32);
  hipLaunchKernelGGL(k_hist,     dim3(104,5),    dim3(256), 0, stream, obj, ws32, 1);
  hipLaunchKernelGGL(k_scan,     dim3(5),        dim3(256), 0, stream, ws32, 1);
  hipLaunchKernelGGL(k_hist,     dim3(104,5),    dim3(256), 0, stream, obj, ws32, 2);
  hipLaunchKernelGGL(k_scan,     dim3(5),        dim3(256), 0, stream, ws32, 2);
  hipLaunchKernelGGL(k_hist,     dim3(104,5),    dim3(256), 0, stream, obj, ws32, 3);
  hipLaunchKernelGGL(k_scan,     dim3(5),        dim3(256), 0, stream, ws32, 3);
  hipLaunchKernelGGL(k_select,   dim3(512),      dim3(256), 0, stream, obj, ws32);
  hipLaunchKernelGGL(k_eqfix,    dim3(5),        dim3(1024),0, stream, ws32);
  hipLaunchKernelGGL(k_sortlvl,  dim3(5),        dim3(512), 0, stream, obj, ws32);
  hipLaunchKernelGGL(k_decode,   dim3(5),        dim3(1024),0, stream, obj, deltas, anchors, ws32);
  hipLaunchKernelGGL(k_sortglob, dim3(1),        dim3(1024),0, stream, ws32);
  hipLaunchKernelGGL(k_prep,     dim3(20),       dim3(256), 0, stream, ws32);
  hipLaunchKernelGGL(k_mask,     dim3((NSEL*ROWW+255)/256), dim3(256), 0, stream, ws32);
  hipLaunchKernelGGL(k_nms,      dim3(1),        dim3(64),  0, stream, ws32);
  hipLaunchKernelGGL(k_out,      dim3(4),        dim3(256), 0, stream, ws32, out);
}

// Round 3
// 629.633 us; speedup vs baseline: 1.9804x; 1.9804x over previous
//
#include <hip/hip_runtime.h>
#include <hip/hip_bf16.h>
#include <math.h>

// Problem constants (img 2048x2048, strides 4..64, 3 anchors/loc)
#define K_TOP 1000
#define NLEV  5
#define NSEL  5000          // 5 * 1000 candidates
#define NSLOT 5120          // 5 * 1024 slots (1024 stride per level)
#define ROWW  80            // u64 words per NMS mask row (5120 bits)
#define NCH   79            // ceil(5000/64) chunks of 64 candidates
#define ATOT  1047552
#define BBOX_CLIP_F 4.135166556742356f

// ws layout in u32 units
#define HISTA   0          // 5*2048
#define HISTB   10240
#define HISTC   20480
#define INFO1   30720      // 5*4: [prefix, aboveTotal, need, pad]
#define INFO2   30740
#define INFO3   30760
#define CANDCNT 30780      // 5
#define EQCNT   30785      // 5
#define MAXC    30790      // 1 (float bits)
#define KEPT    30791      // 1
#define CANDO   30800      // 5*1024 per-level local indices
#define EQO     35920      // 5*2048
#define KEYSO   46160      // u64[8192] -> 16384 u32 (8B aligned)
#define SORTCP  62544      // u32[5120] sorted concat-positions
#define BOXA    67664      // f32[5120][4] clipped boxes per slot
#define VALIDA  88144      // u32[5120]
#define NBSO    93264      // f32[5120][4] offset boxes, sorted order
#define AREAS   113744     // f32[5120]
#define VALSB   118864     // u32[160]: 5000-bit valid mask (u64-aligned)
#define ORDERED 123984     // u32[1024] kept sorted-positions
#define MASKO   125008     // u64[5000*80]  (125008*4 % 8 == 0)

__device__ __forceinline__ int loff(int l){
  return (l==0)?0:(l==1)?786432:(l==2)?983040:(l==3)?1032192:1044480;
}
__device__ __forceinline__ int lsize(int l){
  return (l==0)?786432:(l==1)?196608:(l==2)?49152:(l==3)?12288:3072;
}
// monotonic uint32 key: larger float <-> larger key
__device__ __forceinline__ unsigned fmono(float x){
  unsigned b=__float_as_uint(x);
  return (b&0x80000000u)? ~b : (b|0x80000000u);
}

template<typename T>
__device__ void bitonic_sort(T* sk, int n, int tid, int nth){
  for (int size=2; size<=n; size<<=1){
    for (int stride=size>>1; stride>0; stride>>=1){
      __syncthreads();
      for (int p=tid; p<(n>>1); p+=nth){
        int lo = ((p/stride)*stride<<1) + (p%stride);
        int hi = lo+stride;
        bool asc = ((lo & size)==0);
        T a=sk[lo], b=sk[hi];
        if ((a>b)==asc){ sk[lo]=b; sk[hi]=a; }
      }
    }
  }
  __syncthreads();
}

__global__ void k_init(unsigned* ws32){
  int t=blockIdx.x*blockDim.x+threadIdx.x;
  if (t<30800) ws32[t]=0u;
  if (t<160)   ws32[VALSB+t]=0u;
}

// histogram passes over monotonic objectness key: pass1 bits31..21, pass2 20..10 (given b1), pass3 9..0 (given b1b2)
__global__ void k_hist(const float* __restrict__ obj, unsigned* ws32, int pass){
  int l = blockIdx.y;
  int n = lsize(l), off = loff(l);
  int nbins = (pass==3)?1024:2048;
  unsigned* hist = ws32 + ((pass==1)?HISTA:(pass==2)?HISTB:HISTC) + l*((pass==3)?1024:2048);
  const unsigned* infoPrev = ws32 + ((pass==2)?INFO1:INFO2);
  __shared__ unsigned h[2048];
  for (int t=threadIdx.x; t<nbins; t+=blockDim.x) h[t]=0u;
  __syncthreads();
  unsigned pref = (pass>1)? infoPrev[l*4] : 0u;
  for (int i = blockIdx.x*blockDim.x + threadIdx.x; i<n; i += gridDim.x*blockDim.x){
    unsigned key = fmono(obj[off+i]);
    int bin = -1;
    if (pass==1) bin = key>>21;
    else if (pass==2){ if ((key>>21)==pref) bin=(key>>10)&0x7FF; }
    else { if ((key>>10)==pref) bin = key & 0x3FF; }
    if (bin>=0) atomicAdd(&h[bin],1u);
  }
  __syncthreads();
  for (int t=threadIdx.x; t<nbins; t+=blockDim.x){
    unsigned v=h[t];
    if (v) atomicAdd(&hist[t], v);
  }
}

// descending cumulative scan over hist to find the bin containing the k-th element
__global__ void k_scan(unsigned* ws32, int pass){
  int l = blockIdx.x;
  int tid = threadIdx.x; // 256
  int nbins = (pass==3)?1024:2048;
  const unsigned* hist = ws32 + ((pass==1)?HISTA:(pass==2)?HISTB:HISTC) + l*((pass==3)?1024:2048);
  unsigned* infoOut = ws32 + ((pass==1)?INFO1:(pass==2)?INFO2:INFO3);
  const unsigned* infoPrev = ws32 + ((pass==2)?INFO1:INFO2);
  __shared__ unsigned psum[256];
  __shared__ unsigned sNeed, sAbove, sPrefix;
  if (tid==0){
    if (pass==1){ sNeed=K_TOP; sAbove=0u; sPrefix=0u; }
    else { sNeed=infoPrev[l*4+2]; sAbove=infoPrev[l*4+1]; sPrefix=infoPrev[l*4+0]; }
  }
  __syncthreads();
  int per = nbins/256;
  unsigned local=0;
  for (int r=tid*per; r<tid*per+per; r++) local += hist[nbins-1-r];
  psum[tid]=local; __syncthreads();
  for (int s=1;s<256;s<<=1){
    unsigned v = (tid>=s)? psum[tid-s] : 0u;
    __syncthreads();
    psum[tid]+=v;
    __syncthreads();
  }
  unsigned excl = (tid==0)?0u:psum[tid-1];
  unsigned need = sNeed;
  if (excl < need && psum[tid] >= need){
    unsigned cum = excl;
    for (int r=tid*per; r<tid*per+per; r++){
      unsigned hv = hist[nbins-1-r];
      if (cum + hv >= need){
        unsigned bin = (unsigned)(nbins-1-r);
        unsigned prefix;
        if (pass==1) prefix=bin;
        else if (pass==2) prefix=(sPrefix<<11)|bin;
        else prefix=(sPrefix<<10)|bin;
        infoOut[l*4+0]=prefix;
        infoOut[l*4+1]=sAbove + cum;     // count strictly greater
        infoOut[l*4+2]=need - cum;       // still needed from this bin
        break;
      }
      cum += hv;
    }
  }
}

__global__ void k_select(const float* __restrict__ obj, unsigned* ws32){
  unsigned* cand = ws32 + CANDO;
  unsigned* eq = ws32 + EQO;
  for (int g = blockIdx.x*blockDim.x + threadIdx.x; g<ATOT; g += gridDim.x*blockDim.x){
    int l = (g<786432)?0:(g<983040)?1:(g<1032192)?2:(g<1044480)?3:4;
    unsigned key = fmono(obj[g]);
    unsigned kstar = ws32[INFO3 + l*4];
    if (key > kstar){
      unsigned p = atomicAdd(&ws32[CANDCNT+l],1u);
      if (p<1024u) cand[l*1024+p] = (unsigned)(g - loff(l));
    } else if (key == kstar){
      unsigned p = atomicAdd(&ws32[EQCNT+l],1u);
      if (p<2048u) eq[l*2048+p] = (unsigned)(g - loff(l));
    }
  }
}

// among the elements equal to the k-th key, take the lowest indices (lax.top_k tie rule)
__global__ void k_eqfix(unsigned* ws32){
  int l = blockIdx.x;
  __shared__ unsigned s[2048];
  unsigned cnt = ws32[EQCNT+l]; if (cnt>2048u) cnt=2048u;
  unsigned base = ws32[CANDCNT+l];
  unsigned need = K_TOP - base;
  for (int t=threadIdx.x; t<2048; t+=blockDim.x)
    s[t] = (t<(int)cnt)? ws32[EQO + l*2048 + t] : 0xFFFFFFFFu;
  __syncthreads();
  bitonic_sort<unsigned>(s, 2048, threadIdx.x, blockDim.x);
  for (int t=threadIdx.x; t<(int)need; t+=blockDim.x)
    ws32[CANDO + l*1024 + base + t] = s[t];
}

// sort each level's 1000 selected by (objectness desc, idx asc) -> top_k concat order
__global__ void k_sortlvl(const float* __restrict__ obj, unsigned* ws32){
  int l = blockIdx.x;
  __shared__ unsigned long long k[1024];
  int off = loff(l);
  for (int t=threadIdx.x; t<1024; t+=blockDim.x){
    if (t<K_TOP){
      unsigned idx = ws32[CANDO + l*1024 + t];
      unsigned m = ~fmono(obj[off+idx]);
      k[t] = ((unsigned long long)m<<20) | idx;
    } else k[t] = ~0ULL;
  }
  __syncthreads();
  bitonic_sort<unsigned long long>(k, 1024, threadIdx.x, blockDim.x);
  for (int t=threadIdx.x; t<K_TOP; t+=blockDim.x)
    ws32[CANDO + l*1024 + t] = (unsigned)(k[t] & 0xFFFFFu);
}

// decode + clip + valid + sigmoid score key; replicate fp32 semantics (no FMA contraction)
__global__ void k_decode(const float* __restrict__ obj, const float* __restrict__ deltas,
                         const float* __restrict__ anchors, unsigned* ws32){
  int s = blockIdx.x*blockDim.x + threadIdx.x;  // 5*1024
  int l = s>>10, j = s&1023;
  unsigned long long key = ~0ULL;
  unsigned long long* keys = (unsigned long long*)(ws32+KEYSO);
  if (j < K_TOP){
    unsigned idx = ws32[CANDO + s];
    int g = loff(l) + (int)idx;
    float o = obj[g];
    const float* dd = deltas + 4*(size_t)g;
    const float* aa = anchors + 4*(size_t)g;
    float dx=dd[0], dy=dd[1], dw=dd[2], dh=dd[3];
    float a0=aa[0], a1=aa[1], a2=aa[2], a3=aa[3];
    float w = __fsub_rn(a2,a0), h = __fsub_rn(a3,a1);
    float cx = __fadd_rn(a0, __fmul_rn(0.5f,w));
    float cy = __fadd_rn(a1, __fmul_rn(0.5f,h));
    float dwc = fminf(dw, BBOX_CLIP_F);
    float dhc = fminf(dh, BBOX_CLIP_F);
    float pcx = __fadd_rn(__fmul_rn(dx,w), cx);
    float pcy = __fadd_rn(__fmul_rn(dy,h), cy);
    float pw = __fmul_rn((float)exp((double)dwc), w);
    float ph = __fmul_rn((float)exp((double)dhc), h);
    float x1 = __fsub_rn(pcx, __fmul_rn(0.5f,pw));
    float y1 = __fsub_rn(pcy, __fmul_rn(0.5f,ph));
    float x2 = __fadd_rn(pcx, __fmul_rn(0.5f,pw));
    float y2 = __fadd_rn(pcy, __fmul_rn(0.5f,ph));
    float x1c=fminf(fmaxf(x1,0.0f),2048.0f);
    float y1c=fminf(fmaxf(y1,0.0f),2048.0f);
    float x2c=fminf(fmaxf(x2,0.0f),2048.0f);
    float y2c=fminf(fmaxf(y2,0.0f),2048.0f);
    bool valid = (__fsub_rn(x2c,x1c)>=0.001f) && (__fsub_rn(y2c,y1c)>=0.001f);
    float* bx = (float*)(ws32+BOXA) + 4*s;
    bx[0]=x1c; bx[1]=y1c; bx[2]=x2c; bx[3]=y2c;
    ws32[VALIDA+s] = valid?1u:0u;
    double sg = 1.0/(1.0+exp(-(double)o));
    float sc = (float)sg;
    if (sc < 0.0f) valid = false;   // score >= SCORE_THRESH (always true for sigmoid)
    float masked = valid? sc : -1.0f;
    unsigned sm = ~fmono(masked);
    int cp = l*K_TOP + j;           // concat position
    key = ((unsigned long long)sm<<13) | (unsigned)cp;
    float mx = fmaxf(fmaxf(x1c,y1c),fmaxf(x2c,y2c));
    atomicMax(&ws32[MAXC], __float_as_uint(mx));
  }
  keys[s]=key;
}

// global stable sort: (masked score desc, concat position asc)
__global__ void k_sortglob(unsigned* ws32){
  __shared__ unsigned long long sk[8192];   // 64 KiB
  const unsigned long long* keys = (const unsigned long long*)(ws32+KEYSO);
  for (int t=threadIdx.x; t<8192; t+=blockDim.x)
    sk[t] = (t<NSLOT)? keys[t] : ~0ULL;
  __syncthreads();
  bitonic_sort<unsigned long long>(sk, 8192, threadIdx.x, blockDim.x);
  for (int t=threadIdx.x; t<NSEL; t+=blockDim.x)
    ws32[SORTCP+t] = (unsigned)(sk[t] & 0x1FFFULL);
}

// gather sorted candidates, apply level offsets (exactly as reference), areas, valid bitmask
__global__ void k_prep(unsigned* ws32){
  int i = blockIdx.x*blockDim.x + threadIdx.x;
  if (i>=NSEL) return;
  unsigned cp = ws32[SORTCP+i];
  int l = cp/1000, j = cp - l*1000;
  int s = (l<<10)|j;
  const float* bx = (const float*)(ws32+BOXA) + 4*s;
  float mc = __uint_as_float(ws32[MAXC]);
  float offv = __fmul_rn((float)l, __fadd_rn(mc,1.0f));
  float n0=__fadd_rn(bx[0],offv), n1=__fadd_rn(bx[1],offv);
  float n2=__fadd_rn(bx[2],offv), n3=__fadd_rn(bx[3],offv);
  float* nb = (float*)(ws32+NBSO) + 4*i;
  nb[0]=n0; nb[1]=n1; nb[2]=n2; nb[3]=n3;
  ((float*)(ws32+AREAS))[i] = __fmul_rn(__fsub_rn(n2,n0), __fsub_rn(n3,n1));
  if (ws32[VALIDA+s]) atomicOr(&ws32[VALSB + (i>>5)], 1u<<(i&31));
}

// suppression bitmask rows: bit j of row i => IoU(i,j) > 0.7 (reference arithmetic)
__global__ void k_mask(unsigned* ws32){
  int t = blockIdx.x*blockDim.x + threadIdx.x;
  if (t >= NSEL*ROWW) return;
  int i = t/ROWW, w = t - i*ROWW;
  const float* nbS = (const float*)(ws32+NBSO);
  const float* areaS = (const float*)(ws32+AREAS);
  unsigned long long* mask = (unsigned long long*)(ws32+MASKO);
  float bx1=nbS[4*i], by1=nbS[4*i+1], bx2=nbS[4*i+2], by2=nbS[4*i+3];
  float ai=areaS[i];
  unsigned long long word=0ULL;
  int jbase=w*64;
  #pragma unroll 4
  for (int bj=0; bj<64; bj++){
    int j=jbase+bj;
    if (j>=NSEL) break;
    float iw = fmaxf(__fsub_rn(fminf(nbS[4*j+2],bx2), fmaxf(nbS[4*j+0],bx1)),0.0f);
    float ih = fmaxf(__fsub_rn(fminf(nbS[4*j+3],by2), fmaxf(nbS[4*j+1],by1)),0.0f);
    float inter=__fmul_rn(iw,ih);
    float iou=__fdiv_rn(inter, __fsub_rn(__fadd_rn(areaS[j],ai),inter));
    if (iou>0.7f) word |= (1ULL<<bj);
  }
  mask[(size_t)i*ROWW + w]=word;
}

__device__ __forceinline__ unsigned long long readlane64(unsigned long long v, int l){
  unsigned lo = (unsigned)__builtin_amdgcn_readlane((int)(unsigned)(v & 0xFFFFFFFFULL), l);
  unsigned hi = (unsigned)__builtin_amdgcn_readlane((int)(unsigned)(v >> 32), l);
  return (((unsigned long long)hi)<<32) | lo;
}

// chunk-64 ballot NMS: serial chain is pure register/SALU fixed-point iteration.
// IoU symmetry => lane j's row word IS its incoming-suppression column.
__global__ void __launch_bounds__(64) k_nms(unsigned* ws32){
  const unsigned long long* mask = (const unsigned long long*)(ws32+MASKO);
  const unsigned long long* validw = (const unsigned long long*)(ws32+VALSB);
  int lane = threadIdx.x;
  unsigned long long rem0=0ULL, rem1=0ULL;  // lane holds removed-mask word lane; word 64+lane for lane<16
  unsigned long long lower = (lane==0)?0ULL:(~0ULL >> (64-lane)); // bits strictly below my lane
  int rank=0;

  // software prefetch of chunk-invariant loads
  int row0 = lane; if (row0 > NSEL-1) row0 = NSEL-1;
  unsigned long long intra_next = mask[(size_t)row0*ROWW + 0];
  unsigned long long val_next   = validw[0];

  for (int c=0;c<NCH;c++){
    unsigned long long intra = intra_next;
    unsigned long long valc  = val_next;
    if (c+1 < NCH){
      int rown = 64*(c+1) + lane; if (rown > NSEL-1) rown = NSEL-1;
      intra_next = mask[(size_t)rown*ROWW + (c+1)];
      val_next   = validw[c+1];
    }
    unsigned long long nd = intra & lower;   // smaller-index in-chunk suppressors of me
    // current removed word c (uniform)
    unsigned long long remc = readlane64((c<64)?rem0:rem1, (c<64)?c:(c-64));
    unsigned long long alive = valc & ~remc;
    bool al = (alive>>lane)&1ULL;
    // fixed-point iteration -> unique greedy solution
    unsigned long long kept = alive;
    for (int it=0; it<96; ++it){
      bool sup = (kept & nd) != 0ULL;
      unsigned long long nk = __ballot(al && !sup);
      if (nk == kept) break;
      kept = nk;
    }
    // record kept (ascending index == greedy keep order)
    if ((kept>>lane)&1ULL){
      int pos = rank + (int)__popcll(kept & lower);
      if (pos < K_TOP) ws32[ORDERED+pos] = (unsigned)(64*c+lane);
    }
    rank += (int)__popcll(kept);
    // OR kept rows into removed mask; batched for pipelined loads (uniform branches)
    #pragma unroll
    for (int i0=0;i0<64;i0+=16){
      unsigned kb = (unsigned)((kept>>i0)&0xFFFFULL);
      unsigned long long t0[16], t1[16];
      #pragma unroll
      for (int q=0;q<16;q++){
        t0[q]=0ULL; t1[q]=0ULL;
        if ((kb>>q)&1u){
          const unsigned long long* rowp = mask + (size_t)(64*c+i0+q)*ROWW;
          t0[q] = rowp[lane];
          if (lane<16) t1[q] = rowp[64+lane];
        }
      }
      #pragma unroll
      for (int q=0;q<16;q++){ rem0 |= t0[q]; rem1 |= t1[q]; }
    }
  }
  if (lane==0) ws32[KEPT] = (unsigned)((rank>K_TOP)?K_TOP:rank);
}

__global__ void k_out(const unsigned* __restrict__ ws32, float* __restrict__ out){
  int r = blockIdx.x*blockDim.x + threadIdx.x;
  if (r>=K_TOP) return;
  unsigned cnt = ws32[KEPT];
  float4 v = make_float4(0.f,0.f,0.f,0.f);
  if (r < (int)cnt){
    unsigned i = ws32[ORDERED + r];
    unsigned cp = ws32[SORTCP + i];
    int l = cp/1000, j = cp - l*1000;
    int s = (l<<10)|j;
    const float* b = (const float*)(ws32+BOXA) + 4*s;
    v = make_float4(b[0],b[1],b[2],b[3]);
  }
  ((float4*)out)[r] = v;
}

extern "C" void kernel_launch(void* const* d_in, const int* in_sizes, int n_in,
                              void* d_out, int out_size, void* d_ws, size_t ws_size,
                              hipStream_t stream){
  const float* obj     = (const float*)d_in[0];
  const float* deltas  = (const float*)d_in[1];
  const float* anchors = (const float*)d_in[2];
  unsigned* ws32 = (unsigned*)d_ws;
  float* out = (float*)d_out;
  (void)in_sizes; (void)n_in; (void)out_size; (void)ws_size;

  hipLaunchKernelGGL(k_init,     dim3(128),      dim3(256), 0, stream, ws32);
  hipLaunchKernelGGL(k_hist,     dim3(104,5),    dim3(256), 0, stream, obj, ws32, 1);
  hipLaunchKernelGGL(k_scan,     dim3(5),        dim3(256), 0, stream, ws32, 1);
  hipLaunchKernelGGL(k_hist,     dim3(104,5),    dim3(256), 0, stream, obj, ws32, 2);
  hipLaunchKernelGGL(k_scan,     dim3(5),        dim3(256), 0, stream, ws32, 2);
  hipLaunchKernelGGL(k_hist,     dim3(104,5),    dim3(256), 0, stream, obj, ws32, 3);
  hipLaunchKernelGGL(k_scan,     dim3(5),        dim3(256), 0, stream, ws32, 3);
  hipLaunchKernelGGL(k_select,   dim3(512),      dim3(256), 0, stream, obj, ws32);
  hipLaunchKernelGGL(k_eqfix,    dim3(5),        dim3(1024),0, stream, ws32);
  hipLaunchKernelGGL(k_sortlvl,  dim3(5),        dim3(512), 0, stream, obj, ws32);
  hipLaunchKernelGGL(k_decode,   dim3(5),        dim3(1024),0, stream, obj, deltas, anchors, ws32);
  hipLaunchKernelGGL(k_sortglob, dim3(1),        dim3(1024),0, stream, ws32);
  hipLaunchKernelGGL(k_prep,     dim3(20),       dim3(256), 0, stream, ws32);
  hipLaunchKernelGGL(k_mask,     dim3((NSEL*ROWW+255)/256), dim3(256), 0, stream, ws32);
  hipLaunchKernelGGL(k_nms,      dim3(1),        dim3(64),  0, stream, ws32);
  hipLaunchKernelGGL(k_out,      dim3(4),        dim3(256), 0, stream, ws32, out);
}

// Round 6
// 336.481 us; speedup vs baseline: 3.7058x; 1.8712x over previous
//
#include <hip/hip_runtime.h>
#include <hip/hip_bf16.h>
#include <math.h>

// Problem constants (img 2048x2048, strides 4..64, 3 anchors/loc)
#define K_TOP 1000
#define NLEV  5
#define NSEL  5000          // 5 * 1000 candidates
#define NSLOT 5120          // 5 * 1024 slots (1024 stride per level)
#define NCH   79            // ceil(5000/64) chunks of 64 candidates
#define NP    5000          // u64 row stride of transposed mask: maskT[w*NP + i]
#define NW    80            // allocated word-rows (0..78 used)
#define ATOT  1047552
#define BBOX_CLIP_F 4.135166556742356f

// ws layout in u32 units
#define HISTA   0          // 5*2048
#define HISTB   10240
#define HISTC   20480
#define INFO1   30720      // 5*4: [prefix, aboveTotal, need, pad]
#define INFO2   30740
#define INFO3   30760
#define CANDCNT 30780      // 5
#define EQCNT   30785      // 5
#define MAXC    30790      // 1 (float bits)
#define KEPT    30791      // 1
#define CANDO   30800      // 5*1024 per-level local indices
#define EQO     35920      // 5*2048
#define KEYSO   46160      // u64[8192] -> 16384 u32 (8B aligned)
#define SORTCP  62544      // u32[5120] sorted concat-positions
#define BOXA    67664      // f32[5120][4] clipped boxes per slot
#define VALIDA  88144      // u32[5120]
#define NBSO    93264      // f32[5120][4] offset boxes, sorted order
#define AREAS   113744     // f32[5120]
#define VALSB   118864     // u32[160]: 5000-bit valid mask (u64-aligned)
#define ORDERED 123984     // u32[1024] kept sorted-positions
#define MASKO   125008     // u64[NW*NP] transposed mask (byte off 500032, 16B-aligned)

__device__ __forceinline__ int loff(int l){
  return (l==0)?0:(l==1)?786432:(l==2)?983040:(l==3)?1032192:1044480;
}
__device__ __forceinline__ int lsize(int l){
  return (l==0)?786432:(l==1)?196608:(l==2)?49152:(l==3)?12288:3072;
}
// monotonic uint32 key: larger float <-> larger key
__device__ __forceinline__ unsigned fmono(float x){
  unsigned b=__float_as_uint(x);
  return (b&0x80000000u)? ~b : (b|0x80000000u);
}

template<typename T>
__device__ void bitonic_sort(T* sk, int n, int tid, int nth){
  for (int size=2; size<=n; size<<=1){
    for (int stride=size>>1; stride>0; stride>>=1){
      __syncthreads();
      for (int p=tid; p<(n>>1); p+=nth){
        int lo = ((p/stride)*stride<<1) + (p%stride);
        int hi = lo+stride;
        bool asc = ((lo & size)==0);
        T a=sk[lo], b=sk[hi];
        if ((a>b)==asc){ sk[lo]=b; sk[hi]=a; }
      }
    }
  }
  __syncthreads();
}

__global__ void k_init(unsigned* ws32){
  int t=blockIdx.x*blockDim.x+threadIdx.x;
  if (t<30800) ws32[t]=0u;
  if (t<160)   ws32[VALSB+t]=0u;
}

// histogram passes over monotonic objectness key: pass1 bits31..21, pass2 20..10 (given b1), pass3 9..0 (given b1b2)
__global__ void k_hist(const float* __restrict__ obj, unsigned* ws32, int pass){
  int l = blockIdx.y;
  int n = lsize(l), off = loff(l);
  int nbins = (pass==3)?1024:2048;
  unsigned* hist = ws32 + ((pass==1)?HISTA:(pass==2)?HISTB:HISTC) + l*((pass==3)?1024:2048);
  const unsigned* infoPrev = ws32 + ((pass==2)?INFO1:INFO2);
  __shared__ unsigned h[2048];
  for (int t=threadIdx.x; t<nbins; t+=blockDim.x) h[t]=0u;
  __syncthreads();
  unsigned pref = (pass>1)? infoPrev[l*4] : 0u;
  for (int i = blockIdx.x*blockDim.x + threadIdx.x; i<n; i += gridDim.x*blockDim.x){
    unsigned key = fmono(obj[off+i]);
    int bin = -1;
    if (pass==1) bin = key>>21;
    else if (pass==2){ if ((key>>21)==pref) bin=(key>>10)&0x7FF; }
    else { if ((key>>10)==pref) bin = key & 0x3FF; }
    if (bin>=0) atomicAdd(&h[bin],1u);
  }
  __syncthreads();
  for (int t=threadIdx.x; t<nbins; t+=blockDim.x){
    unsigned v=h[t];
    if (v) atomicAdd(&hist[t], v);
  }
}

// descending cumulative scan over hist to find the bin containing the k-th element
__global__ void k_scan(unsigned* ws32, int pass){
  int l = blockIdx.x;
  int tid = threadIdx.x; // 256
  int nbins = (pass==3)?1024:2048;
  const unsigned* hist = ws32 + ((pass==1)?HISTA:(pass==2)?HISTB:HISTC) + l*((pass==3)?1024:2048);
  unsigned* infoOut = ws32 + ((pass==1)?INFO1:(pass==2)?INFO2:INFO3);
  const unsigned* infoPrev = ws32 + ((pass==2)?INFO1:INFO2);
  __shared__ unsigned psum[256];
  __shared__ unsigned sNeed, sAbove, sPrefix;
  if (tid==0){
    if (pass==1){ sNeed=K_TOP; sAbove=0u; sPrefix=0u; }
    else { sNeed=infoPrev[l*4+2]; sAbove=infoPrev[l*4+1]; sPrefix=infoPrev[l*4+0]; }
  }
  __syncthreads();
  int per = nbins/256;
  unsigned local=0;
  for (int r=tid*per; r<tid*per+per; r++) local += hist[nbins-1-r];
  psum[tid]=local; __syncthreads();
  for (int s=1;s<256;s<<=1){
    unsigned v = (tid>=s)? psum[tid-s] : 0u;
    __syncthreads();
    psum[tid]+=v;
    __syncthreads();
  }
  unsigned excl = (tid==0)?0u:psum[tid-1];
  unsigned need = sNeed;
  if (excl < need && psum[tid] >= need){
    unsigned cum = excl;
    for (int r=tid*per; r<tid*per+per; r++){
      unsigned hv = hist[nbins-1-r];
      if (cum + hv >= need){
        unsigned bin = (unsigned)(nbins-1-r);
        unsigned prefix;
        if (pass==1) prefix=bin;
        else if (pass==2) prefix=(sPrefix<<11)|bin;
        else prefix=(sPrefix<<10)|bin;
        infoOut[l*4+0]=prefix;
        infoOut[l*4+1]=sAbove + cum;     // count strictly greater
        infoOut[l*4+2]=need - cum;       // still needed from this bin
        break;
      }
      cum += hv;
    }
  }
}

__global__ void k_select(const float* __restrict__ obj, unsigned* ws32){
  unsigned* cand = ws32 + CANDO;
  unsigned* eq = ws32 + EQO;
  for (int g = blockIdx.x*blockDim.x + threadIdx.x; g<ATOT; g += gridDim.x*blockDim.x){
    int l = (g<786432)?0:(g<983040)?1:(g<1032192)?2:(g<1044480)?3:4;
    unsigned key = fmono(obj[g]);
    unsigned kstar = ws32[INFO3 + l*4];
    if (key > kstar){
      unsigned p = atomicAdd(&ws32[CANDCNT+l],1u);
      if (p<1024u) cand[l*1024+p] = (unsigned)(g - loff(l));
    } else if (key == kstar){
      unsigned p = atomicAdd(&ws32[EQCNT+l],1u);
      if (p<2048u) eq[l*2048+p] = (unsigned)(g - loff(l));
    }
  }
}

// among the elements equal to the k-th key, take the lowest indices (lax.top_k tie rule)
__global__ void k_eqfix(unsigned* ws32){
  int l = blockIdx.x;
  __shared__ unsigned s[2048];
  unsigned cnt = ws32[EQCNT+l]; if (cnt>2048u) cnt=2048u;
  unsigned base = ws32[CANDCNT+l];
  unsigned need = K_TOP - base;
  for (int t=threadIdx.x; t<2048; t+=blockDim.x)
    s[t] = (t<(int)cnt)? ws32[EQO + l*2048 + t] : 0xFFFFFFFFu;
  __syncthreads();
  bitonic_sort<unsigned>(s, 2048, threadIdx.x, blockDim.x);
  for (int t=threadIdx.x; t<(int)need; t+=blockDim.x)
    ws32[CANDO + l*1024 + base + t] = s[t];
}

// sort each level's 1000 selected by (objectness desc, idx asc) -> top_k concat order
__global__ void k_sortlvl(const float* __restrict__ obj, unsigned* ws32){
  int l = blockIdx.x;
  __shared__ unsigned long long k[1024];
  int off = loff(l);
  for (int t=threadIdx.x; t<1024; t+=blockDim.x){
    if (t<K_TOP){
      unsigned idx = ws32[CANDO + l*1024 + t];
      unsigned m = ~fmono(obj[off+idx]);
      k[t] = ((unsigned long long)m<<20) | idx;
    } else k[t] = ~0ULL;
  }
  __syncthreads();
  bitonic_sort<unsigned long long>(k, 1024, threadIdx.x, blockDim.x);
  for (int t=threadIdx.x; t<K_TOP; t+=blockDim.x)
    ws32[CANDO + l*1024 + t] = (unsigned)(k[t] & 0xFFFFFu);
}

// decode + clip + valid + sigmoid score key; replicate fp32 semantics (no FMA contraction)
__global__ void k_decode(const float* __restrict__ obj, const float* __restrict__ deltas,
                         const float* __restrict__ anchors, unsigned* ws32){
  int s = blockIdx.x*blockDim.x + threadIdx.x;  // 5*1024
  int l = s>>10, j = s&1023;
  unsigned long long key = ~0ULL;
  unsigned long long* keys = (unsigned long long*)(ws32+KEYSO);
  if (j < K_TOP){
    unsigned idx = ws32[CANDO + s];
    int g = loff(l) + (int)idx;
    float o = obj[g];
    const float* dd = deltas + 4*(size_t)g;
    const float* aa = anchors + 4*(size_t)g;
    float dx=dd[0], dy=dd[1], dw=dd[2], dh=dd[3];
    float a0=aa[0], a1=aa[1], a2=aa[2], a3=aa[3];
    float w = __fsub_rn(a2,a0), h = __fsub_rn(a3,a1);
    float cx = __fadd_rn(a0, __fmul_rn(0.5f,w));
    float cy = __fadd_rn(a1, __fmul_rn(0.5f,h));
    float dwc = fminf(dw, BBOX_CLIP_F);
    float dhc = fminf(dh, BBOX_CLIP_F);
    float pcx = __fadd_rn(__fmul_rn(dx,w), cx);
    float pcy = __fadd_rn(__fmul_rn(dy,h), cy);
    float pw = __fmul_rn((float)exp((double)dwc), w);
    float ph = __fmul_rn((float)exp((double)dhc), h);
    float x1 = __fsub_rn(pcx, __fmul_rn(0.5f,pw));
    float y1 = __fsub_rn(pcy, __fmul_rn(0.5f,ph));
    float x2 = __fadd_rn(pcx, __fmul_rn(0.5f,pw));
    float y2 = __fadd_rn(pcy, __fmul_rn(0.5f,ph));
    float x1c=fminf(fmaxf(x1,0.0f),2048.0f);
    float y1c=fminf(fmaxf(y1,0.0f),2048.0f);
    float x2c=fminf(fmaxf(x2,0.0f),2048.0f);
    float y2c=fminf(fmaxf(y2,0.0f),2048.0f);
    bool valid = (__fsub_rn(x2c,x1c)>=0.001f) && (__fsub_rn(y2c,y1c)>=0.001f);
    float* bx = (float*)(ws32+BOXA) + 4*s;
    bx[0]=x1c; bx[1]=y1c; bx[2]=x2c; bx[3]=y2c;
    ws32[VALIDA+s] = valid?1u:0u;
    double sg = 1.0/(1.0+exp(-(double)o));
    float sc = (float)sg;
    if (sc < 0.0f) valid = false;   // score >= SCORE_THRESH (always true for sigmoid)
    float masked = valid? sc : -1.0f;
    unsigned sm = ~fmono(masked);
    int cp = l*K_TOP + j;           // concat position
    key = ((unsigned long long)sm<<13) | (unsigned)cp;
    float mx = fmaxf(fmaxf(x1c,y1c),fmaxf(x2c,y2c));
    atomicMax(&ws32[MAXC], __float_as_uint(mx));
  }
  keys[s]=key;
}

// global stable sort: (masked score desc, concat position asc)
__global__ void k_sortglob(unsigned* ws32){
  __shared__ unsigned long long sk[8192];   // 64 KiB
  const unsigned long long* keys = (const unsigned long long*)(ws32+KEYSO);
  for (int t=threadIdx.x; t<8192; t+=blockDim.x)
    sk[t] = (t<NSLOT)? keys[t] : ~0ULL;
  __syncthreads();
  bitonic_sort<unsigned long long>(sk, 8192, threadIdx.x, blockDim.x);
  for (int t=threadIdx.x; t<NSEL; t+=blockDim.x)
    ws32[SORTCP+t] = (unsigned)(sk[t] & 0x1FFFULL);
}

// gather sorted candidates, apply level offsets (exactly as reference), areas, valid bitmask
__global__ void k_prep(unsigned* ws32){
  int i = blockIdx.x*blockDim.x + threadIdx.x;
  if (i>=NSEL) return;
  unsigned cp = ws32[SORTCP+i];
  int l = cp/1000, j = cp - l*1000;
  int s = (l<<10)|j;
  const float* bx = (const float*)(ws32+BOXA) + 4*s;
  float mc = __uint_as_float(ws32[MAXC]);
  float offv = __fmul_rn((float)l, __fadd_rn(mc,1.0f));
  float n0=__fadd_rn(bx[0],offv), n1=__fadd_rn(bx[1],offv);
  float n2=__fadd_rn(bx[2],offv), n3=__fadd_rn(bx[3],offv);
  float* nb = (float*)(ws32+NBSO) + 4*i;
  nb[0]=n0; nb[1]=n1; nb[2]=n2; nb[3]=n3;
  ((float*)(ws32+AREAS))[i] = __fmul_rn(__fsub_rn(n2,n0), __fsub_rn(n3,n1));
  if (ws32[VALIDA+s]) atomicOr(&ws32[VALSB + (i>>5)], 1u<<(i&31));
}

// transposed suppression mask: maskT[w*NP + i] bit b = IoU(i, 64w+b) > 0.7
// (reference orientation: denominator = areas[j] + areas[i], j = 64w+b)
__global__ void k_mask(unsigned* ws32){
  int i = blockIdx.x*64 + threadIdx.x;
  int w = blockIdx.y;
  if (i >= NSEL) return;
  const float* nbS = (const float*)(ws32+NBSO);
  const float* areaS = (const float*)(ws32+AREAS);
  unsigned long long* maskT = (unsigned long long*)(ws32+MASKO);
  float bx1=nbS[4*i], by1=nbS[4*i+1], bx2=nbS[4*i+2], by2=nbS[4*i+3];
  float ai=areaS[i];
  unsigned long long word=0ULL;
  int jbase=w*64;
  int jend = jbase+64; if (jend>NSEL) jend=NSEL;
  for (int j=jbase; j<jend; ++j){
    float iw = fmaxf(__fsub_rn(fminf(nbS[4*j+2],bx2), fmaxf(nbS[4*j+0],bx1)),0.0f);
    float ih = fmaxf(__fsub_rn(fminf(nbS[4*j+3],by2), fmaxf(nbS[4*j+1],by1)),0.0f);
    float inter=__fmul_rn(iw,ih);
    float iou=__fdiv_rn(inter, __fsub_rn(__fadd_rn(areaS[j],ai),inter));
    if (iou>0.7f) word |= (1ULL<<(j-jbase));
  }
  maskT[(size_t)w*NP + i]=word;
}

// chunk-64 gather NMS with early exit at rank>=1000 (exact: kept boxes with
// rank>=1000 are dropped by the reference scatter, and cannot affect earlier ones).
// Lane owns column q=64c+lane. sup = OR_{w<c}(maskT[w][q] & Kb[w]) via plain
// coalesced per-lane loads (unroll 8 for ILP). Intra-chunk greedy via ballot
// fixed-point (converges to the unique greedy solution; bounded iterations).
__global__ void __launch_bounds__(64) k_nms(unsigned* ws32){
  const unsigned long long* maskT = (const unsigned long long*)(ws32+MASKO);
  const unsigned long long* validw = (const unsigned long long*)(ws32+VALSB);
  int lane = threadIdx.x;
  __shared__ unsigned long long Kb[NW];   // kept word per finished chunk
  __shared__ unsigned long long Vb[NW];   // valid words
  if (lane < NCH) Vb[lane] = validw[lane];
  __syncthreads();
  unsigned long long lower = (lane==0)?0ULL:(~0ULL >> (64-lane));
  int rank=0;
  for (int c=0;c<NCH;c++){
    int q = (c<<6) + lane;
    size_t qc = (q < NSEL)? (size_t)q : (size_t)(NSEL-1);  // clamped lanes have valid=0, never kept
    unsigned long long sup=0ULL;
    #pragma unroll 8
    for (int w=0; w<c; ++w)
      sup |= maskT[(size_t)w*NP + qc] & Kb[w];
    unsigned long long intra = maskT[(size_t)c*NP + qc];
    unsigned long long valc  = Vb[c];
    bool al = ((valc>>lane)&1ULL) && (sup==0ULL);
    unsigned long long nd = intra & lower;   // smaller-index in-chunk suppressors
    unsigned long long kept = __ballot(al);
    for (int it=0; it<96; ++it){
      bool s2 = (kept & nd) != 0ULL;
      unsigned long long nk = __ballot(al && !s2);
      if (nk==kept) break;
      kept = nk;
    }
    if ((kept>>lane)&1ULL){
      int pos = rank + (int)__popcll(kept & lower);
      if (pos < K_TOP) ws32[ORDERED+pos] = (unsigned)q;
    }
    rank += (int)__popcll(kept);
    if (rank >= K_TOP) break;
    if (lane==0) Kb[c] = kept;
    __syncthreads();
  }
  if (lane==0) ws32[KEPT] = (unsigned)((rank>K_TOP)?K_TOP:rank);
}

__global__ void k_out(const unsigned* __restrict__ ws32, float* __restrict__ out){
  int r = blockIdx.x*blockDim.x + threadIdx.x;
  if (r>=K_TOP) return;
  unsigned cnt = ws32[KEPT];
  float4 v = make_float4(0.f,0.f,0.f,0.f);
  if (r < (int)cnt){
    unsigned i = ws32[ORDERED + r];
    unsigned cp = ws32[SORTCP + i];
    int l = cp/1000, j = cp - l*1000;
    int s = (l<<10)|j;
    const float* b = (const float*)(ws32+BOXA) + 4*s;
    v = make_float4(b[0],b[1],b[2],b[3]);
  }
  ((float4*)out)[r] = v;
}

extern "C" void kernel_launch(void* const* d_in, const int* in_sizes, int n_in,
                              void* d_out, int out_size, void* d_ws, size_t ws_size,
                              hipStream_t stream){
  const float* obj     = (const float*)d_in[0];
  const float* deltas  = (const float*)d_in[1];
  const float* anchors = (const float*)d_in[2];
  unsigned* ws32 = (unsigned*)d_ws;
  float* out = (float*)d_out;
  (void)in_sizes; (void)n_in; (void)out_size; (void)ws_size;

  hipLaunchKernelGGL(k_init,     dim3(128),      dim3(256), 0, stream, ws32);
  hipLaunchKernelGGL(k_hist,     dim3(104,5),    dim3(256), 0, stream, obj, ws32, 1);
  hipLaunchKernelGGL(k_scan,     dim3(5),        dim3(256), 0, stream, ws32, 1);
  hipLaunchKernelGGL(k_hist,     dim3(104,5),    dim3(256), 0, stream, obj, ws32, 2);
  hipLaunchKernelGGL(k_scan,     dim3(5),        dim3(256), 0, stream, ws32, 2);
  hipLaunchKernelGGL(k_hist,     dim3(104,5),    dim3(256), 0, stream, obj, ws32, 3);
  hipLaunchKernelGGL(k_scan,     dim3(5),        dim3(256), 0, stream, ws32, 3);
  hipLaunchKernelGGL(k_select,   dim3(512),      dim3(256), 0, stream, obj, ws32);
  hipLaunchKernelGGL(k_eqfix,    dim3(5),        dim3(1024),0, stream, ws32);
  hipLaunchKernelGGL(k_sortlvl,  dim3(5),        dim3(512), 0, stream, obj, ws32);
  hipLaunchKernelGGL(k_decode,   dim3(5),        dim3(1024),0, stream, obj, deltas, anchors, ws32);
  hipLaunchKernelGGL(k_sortglob, dim3(1),        dim3(1024),0, stream, ws32);
  hipLaunchKernelGGL(k_prep,     dim3(20),       dim3(256), 0, stream, ws32);
  hipLaunchKernelGGL(k_mask,     dim3(79,79),    dim3(64),  0, stream, ws32);
  hipLaunchKernelGGL(k_nms,      dim3(1),        dim3(64),  0, stream, ws32);
  hipLaunchKernelGGL(k_out,      dim3(4),        dim3(256), 0, stream, ws32, out);
}

// Round 7
// 197.534 us; speedup vs baseline: 6.3125x; 1.7034x over previous
//
#include <hip/hip_runtime.h>
#include <hip/hip_bf16.h>
#include <math.h>

// Problem constants (img 2048x2048, strides 4..64, 3 anchors/loc)
#define K_TOP 1000
#define NLEV  5
#define NSEL  5000          // 5 * 1000 candidates
#define NSLOT 5120          // 5 * 1024 slots (1024 stride per level)
#define NCH   79            // ceil(5000/64) chunks of 64 candidates
#define NP    5000          // u64 row stride of transposed mask: maskT[w*NP + i]
#define NW    80            // allocated word-rows (0..78 used)
#define ATOT  1047552
#define BBOX_CLIP_F 4.135166556742356f

// ws layout in u32 units
#define KEYS2   0          // u64[5000] per-level partitioned keys (reuses HISTA; free after pass1)
#define HISTA   0          // 5*2048 (pass-1 hist; KEYS2 reuses this after select)
#define HISTB   10240
#define HISTC   20480
#define INFO1   30720      // 5*4: [prefix, aboveTotal, need, pad]
#define INFO2   30740
#define INFO3   30760
#define CANDCNT 30784      // 5   (own 128B line, away from INFO3 - atomic ping-pong fix)
#define EQCNT   30789      // 5
#define MAXC    30794      // 1 (float bits)
#define KEPT    30795      // 1
#define CANDO   30800      // 5*1024 per-level local indices
#define EQO     35920      // 5*2048
#define KEYSO   46160      // u64[8192] -> 16384 u32 (8B aligned)
#define SORTCP  62544      // u32[5120] sorted concat-positions
#define BOXA    67664      // f32[5120][4] clipped boxes per slot
#define VALIDA  88144      // u32[5120]
#define NBSO    93264      // f32[5120][4] offset boxes, sorted order
#define AREAS   113744     // f32[5120]
#define VALSB   118864     // u32[160]: 5000-bit valid mask (u64-aligned)
#define ORDERED 123984     // u32[1024] kept sorted-positions
#define MASKO   125008     // u64[NW*NP] transposed mask (byte off 500032, 16B-aligned)

__device__ __forceinline__ int loff(int l){
  return (l==0)?0:(l==1)?786432:(l==2)?983040:(l==3)?1032192:1044480;
}
__device__ __forceinline__ int lsize(int l){
  return (l==0)?786432:(l==1)?196608:(l==2)?49152:(l==3)?12288:3072;
}
// monotonic uint32 key: larger float <-> larger key
__device__ __forceinline__ unsigned fmono(float x){
  unsigned b=__float_as_uint(x);
  return (b&0x80000000u)? ~b : (b|0x80000000u);
}

template<typename T>
__device__ void bitonic_sort(T* sk, int n, int tid, int nth){
  for (int size=2; size<=n; size<<=1){
    for (int stride=size>>1; stride>0; stride>>=1){
      __syncthreads();
      for (int p=tid; p<(n>>1); p+=nth){
        int lo = ((p/stride)*stride<<1) + (p%stride);
        int hi = lo+stride;
        bool asc = ((lo & size)==0);
        T a=sk[lo], b=sk[hi];
        if ((a>b)==asc){ sk[lo]=b; sk[hi]=a; }
      }
    }
  }
  __syncthreads();
}

__global__ void k_init(unsigned* ws32){
  int t=blockIdx.x*blockDim.x+threadIdx.x;
  if (t<30800) ws32[t]=0u;
  if (t<160)   ws32[VALSB+t]=0u;
}

// histogram passes over monotonic objectness key: pass1 bits31..21, pass2 20..10 (given b1), pass3 9..0 (given b1b2)
__global__ void k_hist(const float* __restrict__ obj, unsigned* ws32, int pass){
  int l = blockIdx.y;
  int n = lsize(l), off = loff(l);
  int nbins = (pass==3)?1024:2048;
  unsigned* hist = ws32 + ((pass==1)?HISTA:(pass==2)?HISTB:HISTC) + l*((pass==3)?1024:2048);
  const unsigned* infoPrev = ws32 + ((pass==2)?INFO1:INFO2);
  __shared__ unsigned h[2048];
  for (int t=threadIdx.x; t<nbins; t+=blockDim.x) h[t]=0u;
  __syncthreads();
  unsigned pref = (pass>1)? infoPrev[l*4] : 0u;
  for (int i = blockIdx.x*blockDim.x + threadIdx.x; i<n; i += gridDim.x*blockDim.x){
    unsigned key = fmono(obj[off+i]);
    int bin = -1;
    if (pass==1) bin = key>>21;
    else if (pass==2){ if ((key>>21)==pref) bin=(key>>10)&0x7FF; }
    else { if ((key>>10)==pref) bin = key & 0x3FF; }
    if (bin>=0) atomicAdd(&h[bin],1u);
  }
  __syncthreads();
  for (int t=threadIdx.x; t<nbins; t+=blockDim.x){
    unsigned v=h[t];
    if (v) atomicAdd(&hist[t], v);
  }
}

// descending cumulative scan over hist to find the bin containing the k-th element
__global__ void k_scan(unsigned* ws32, int pass){
  int l = blockIdx.x;
  int tid = threadIdx.x; // 256
  int nbins = (pass==3)?1024:2048;
  const unsigned* hist = ws32 + ((pass==1)?HISTA:(pass==2)?HISTB:HISTC) + l*((pass==3)?1024:2048);
  unsigned* infoOut = ws32 + ((pass==1)?INFO1:(pass==2)?INFO2:INFO3);
  const unsigned* infoPrev = ws32 + ((pass==2)?INFO1:INFO2);
  __shared__ unsigned psum[256];
  __shared__ unsigned sNeed, sAbove, sPrefix;
  if (tid==0){
    if (pass==1){ sNeed=K_TOP; sAbove=0u; sPrefix=0u; }
    else { sNeed=infoPrev[l*4+2]; sAbove=infoPrev[l*4+1]; sPrefix=infoPrev[l*4+0]; }
  }
  __syncthreads();
  int per = nbins/256;
  unsigned local=0;
  for (int r=tid*per; r<tid*per+per; r++) local += hist[nbins-1-r];
  psum[tid]=local; __syncthreads();
  for (int s=1;s<256;s<<=1){
    unsigned v = (tid>=s)? psum[tid-s] : 0u;
    __syncthreads();
    psum[tid]+=v;
    __syncthreads();
  }
  unsigned excl = (tid==0)?0u:psum[tid-1];
  unsigned need = sNeed;
  if (excl < need && psum[tid] >= need){
    unsigned cum = excl;
    for (int r=tid*per; r<tid*per+per; r++){
      unsigned hv = hist[nbins-1-r];
      if (cum + hv >= need){
        unsigned bin = (unsigned)(nbins-1-r);
        unsigned prefix;
        if (pass==1) prefix=bin;
        else if (pass==2) prefix=(sPrefix<<11)|bin;
        else prefix=(sPrefix<<10)|bin;
        infoOut[l*4+0]=prefix;
        infoOut[l*4+1]=sAbove + cum;     // count strictly greater
        infoOut[l*4+2]=need - cum;       // still needed from this bin
        break;
      }
      cum += hv;
    }
  }
}

// wave-aggregated select: kstar hoisted to registers, one atomic per wave per hit.
// Level boundaries and the grid-stride tail are multiples of 64 -> waves never straddle.
__global__ void k_select(const float* __restrict__ obj, unsigned* ws32){
  unsigned ks0=ws32[INFO3+0], ks1=ws32[INFO3+4], ks2=ws32[INFO3+8],
           ks3=ws32[INFO3+12], ks4=ws32[INFO3+16];
  int lane = threadIdx.x & 63;
  unsigned long long lmask = (lane==0)?0ULL:(~0ULL >> (64-lane));
  for (int g = blockIdx.x*blockDim.x + threadIdx.x; g<ATOT; g += gridDim.x*blockDim.x){
    int l = (g<786432)?0:(g<983040)?1:(g<1032192)?2:(g<1044480)?3:4;
    unsigned kstar = (l==0)?ks0:(l==1)?ks1:(l==2)?ks2:(l==3)?ks3:ks4;
    unsigned key = fmono(obj[g]);
    bool isc = key>kstar, ise = key==kstar;
    unsigned long long mc = __ballot(isc);
    unsigned long long me = __ballot(ise);
    if (mc){
      unsigned base=0;
      if (lane==0) base = atomicAdd(&ws32[CANDCNT+l], (unsigned)__popcll(mc));
      base = __shfl(base, 0, 64);
      if (isc){
        unsigned p = base + (unsigned)__popcll(mc & lmask);
        if (p<1024u) ws32[CANDO + l*1024 + p] = (unsigned)(g - loff(l));
      }
    }
    if (me){
      unsigned base=0;
      if (lane==0) base = atomicAdd(&ws32[EQCNT+l], (unsigned)__popcll(me));
      base = __shfl(base, 0, 64);
      if (ise){
        unsigned p = base + (unsigned)__popcll(me & lmask);
        if (p<2048u) ws32[EQO + l*2048 + p] = (unsigned)(g - loff(l));
      }
    }
  }
}

// among the elements equal to the k-th key, take the lowest indices (lax.top_k tie rule)
__global__ void k_eqfix(unsigned* ws32){
  int l = blockIdx.x;
  __shared__ unsigned s[2048];
  unsigned cnt = ws32[EQCNT+l]; if (cnt>2048u) cnt=2048u;
  unsigned base = ws32[CANDCNT+l];
  unsigned need = K_TOP - base;
  for (int t=threadIdx.x; t<2048; t+=blockDim.x)
    s[t] = (t<(int)cnt)? ws32[EQO + l*2048 + t] : 0xFFFFFFFFu;
  __syncthreads();
  bitonic_sort<unsigned>(s, 2048, threadIdx.x, blockDim.x);
  for (int t=threadIdx.x; t<(int)need; t+=blockDim.x)
    ws32[CANDO + l*1024 + base + t] = s[t];
}

// sort each level's 1000 selected by (objectness desc, idx asc) -> top_k concat order
__global__ void k_sortlvl(const float* __restrict__ obj, unsigned* ws32){
  int l = blockIdx.x;
  __shared__ unsigned long long k[1024];
  int off = loff(l);
  for (int t=threadIdx.x; t<1024; t+=blockDim.x){
    if (t<K_TOP){
      unsigned idx = ws32[CANDO + l*1024 + t];
      unsigned m = ~fmono(obj[off+idx]);
      k[t] = ((unsigned long long)m<<20) | idx;
    } else k[t] = ~0ULL;
  }
  __syncthreads();
  bitonic_sort<unsigned long long>(k, 1024, threadIdx.x, blockDim.x);
  for (int t=threadIdx.x; t<K_TOP; t+=blockDim.x)
    ws32[CANDO + l*1024 + t] = (unsigned)(k[t] & 0xFFFFFu);
}

// decode + clip + valid + sigmoid score key; replicate fp32 semantics (no FMA contraction)
__global__ void k_decode(const float* __restrict__ obj, const float* __restrict__ deltas,
                         const float* __restrict__ anchors, unsigned* ws32){
  int s = blockIdx.x*blockDim.x + threadIdx.x;  // 5*1024
  int l = s>>10, j = s&1023;
  unsigned long long key = ~0ULL;
  unsigned long long* keys = (unsigned long long*)(ws32+KEYSO);
  if (j < K_TOP){
    unsigned idx = ws32[CANDO + s];
    int g = loff(l) + (int)idx;
    float o = obj[g];
    const float* dd = deltas + 4*(size_t)g;
    const float* aa = anchors + 4*(size_t)g;
    float dx=dd[0], dy=dd[1], dw=dd[2], dh=dd[3];
    float a0=aa[0], a1=aa[1], a2=aa[2], a3=aa[3];
    float w = __fsub_rn(a2,a0), h = __fsub_rn(a3,a1);
    float cx = __fadd_rn(a0, __fmul_rn(0.5f,w));
    float cy = __fadd_rn(a1, __fmul_rn(0.5f,h));
    float dwc = fminf(dw, BBOX_CLIP_F);
    float dhc = fminf(dh, BBOX_CLIP_F);
    float pcx = __fadd_rn(__fmul_rn(dx,w), cx);
    float pcy = __fadd_rn(__fmul_rn(dy,h), cy);
    float pw = __fmul_rn((float)exp((double)dwc), w);
    float ph = __fmul_rn((float)exp((double)dhc), h);
    float x1 = __fsub_rn(pcx, __fmul_rn(0.5f,pw));
    float y1 = __fsub_rn(pcy, __fmul_rn(0.5f,ph));
    float x2 = __fadd_rn(pcx, __fmul_rn(0.5f,pw));
    float y2 = __fadd_rn(pcy, __fmul_rn(0.5f,ph));
    float x1c=fminf(fmaxf(x1,0.0f),2048.0f);
    float y1c=fminf(fmaxf(y1,0.0f),2048.0f);
    float x2c=fminf(fmaxf(x2,0.0f),2048.0f);
    float y2c=fminf(fmaxf(y2,0.0f),2048.0f);
    bool valid = (__fsub_rn(x2c,x1c)>=0.001f) && (__fsub_rn(y2c,y1c)>=0.001f);
    float* bx = (float*)(ws32+BOXA) + 4*s;
    bx[0]=x1c; bx[1]=y1c; bx[2]=x2c; bx[3]=y2c;
    ws32[VALIDA+s] = valid?1u:0u;
    double sg = 1.0/(1.0+exp(-(double)o));
    float sc = (float)sg;
    if (sc < 0.0f) valid = false;   // score >= SCORE_THRESH (always true for sigmoid)
    float masked = valid? sc : -1.0f;
    unsigned sm = ~fmono(masked);
    int cp = l*K_TOP + j;           // concat position
    key = ((unsigned long long)sm<<13) | (unsigned)cp;
    float mx = fmaxf(fmaxf(x1c,y1c),fmaxf(x2c,y2c));
    atomicMax(&ws32[MAXC], __float_as_uint(mx));
  }
  keys[s]=key;
}

// per-level stable partition: valid (j order) then invalid (j order) == per-level key-ascending.
// (valid: j asc <=> score desc <=> key asc; all valid keys < all invalid keys; invalid share sm, cp asc.)
__global__ void k_part(unsigned* ws32){
  int l = blockIdx.x;
  int t = threadIdx.x;   // 1024
  const unsigned long long* keys = (const unsigned long long*)(ws32+KEYSO);
  unsigned long long* k2 = (unsigned long long*)(ws32+KEYS2);
  __shared__ unsigned pfx[1024];
  __shared__ unsigned nv;
  int s = (l<<10)|t;
  unsigned v = (t<K_TOP)? ws32[VALIDA+s] : 0u;
  pfx[t]=v; __syncthreads();
  for (int st=1; st<1024; st<<=1){
    unsigned x = (t>=st)? pfx[t-st]:0u;
    __syncthreads();
    pfx[t]+=x;
    __syncthreads();
  }
  if (t==1023) nv = pfx[1023];
  __syncthreads();
  if (t<K_TOP){
    unsigned inc = pfx[t];
    unsigned pos = v? (inc-1u) : (nv + (unsigned)t - inc);
    k2[l*K_TOP + pos] = keys[s];
  }
}

// 5-way merge by rank: grank = own pos + sum of lower_bounds in other levels (keys unique via cp).
__global__ void k_merge(unsigned* ws32){
  int l = blockIdx.x;     // 5 blocks x 1024
  int t = threadIdx.x;
  const unsigned long long* k2 = (const unsigned long long*)(ws32+KEYS2);
  __shared__ unsigned long long sk[NLEV][K_TOP];   // 40000 B
  for (int m=0;m<NLEV;m++)
    if (t<K_TOP) sk[m][t] = k2[m*K_TOP+t];
  __syncthreads();
  if (t<K_TOP){
    unsigned long long k = sk[l][t];
    int grank = t;
    #pragma unroll
    for (int m=0;m<NLEV;m++){
      if (m==l) continue;
      int lo=0, hi=K_TOP;
      while (lo<hi){ int mid=(lo+hi)>>1; if (sk[m][mid]<k) lo=mid+1; else hi=mid; }
      grank += lo;
    }
    ws32[SORTCP+grank] = (unsigned)(k & 0x1FFFULL);
  }
}

// gather sorted candidates, apply level offsets (exactly as reference), areas, valid bitmask
__global__ void k_prep(unsigned* ws32){
  int i = blockIdx.x*blockDim.x + threadIdx.x;
  if (i>=NSEL) return;
  unsigned cp = ws32[SORTCP+i];
  int l = cp/1000, j = cp - l*1000;
  int s = (l<<10)|j;
  const float* bx = (const float*)(ws32+BOXA) + 4*s;
  float mc = __uint_as_float(ws32[MAXC]);
  float offv = __fmul_rn((float)l, __fadd_rn(mc,1.0f));
  float n0=__fadd_rn(bx[0],offv), n1=__fadd_rn(bx[1],offv);
  float n2=__fadd_rn(bx[2],offv), n3=__fadd_rn(bx[3],offv);
  float* nb = (float*)(ws32+NBSO) + 4*i;
  nb[0]=n0; nb[1]=n1; nb[2]=n2; nb[3]=n3;
  ((float*)(ws32+AREAS))[i] = __fmul_rn(__fsub_rn(n2,n0), __fsub_rn(n3,n1));
  if (ws32[VALIDA+s]) atomicOr(&ws32[VALSB + (i>>5)], 1u<<(i&31));
}

// transposed suppression mask: maskT[w*NP + i] bit b = IoU(i, 64w+b) > 0.7
__global__ void k_mask(unsigned* ws32){
  int i = blockIdx.x*64 + threadIdx.x;
  int w = blockIdx.y;
  if (i >= NSEL) return;
  const float* nbS = (const float*)(ws32+NBSO);
  const float* areaS = (const float*)(ws32+AREAS);
  unsigned long long* maskT = (unsigned long long*)(ws32+MASKO);
  float bx1=nbS[4*i], by1=nbS[4*i+1], bx2=nbS[4*i+2], by2=nbS[4*i+3];
  float ai=areaS[i];
  unsigned long long word=0ULL;
  int jbase=w*64;
  int jend = jbase+64; if (jend>NSEL) jend=NSEL;
  for (int j=jbase; j<jend; ++j){
    float iw = fmaxf(__fsub_rn(fminf(nbS[4*j+2],bx2), fmaxf(nbS[4*j+0],bx1)),0.0f);
    float ih = fmaxf(__fsub_rn(fminf(nbS[4*j+3],by2), fmaxf(nbS[4*j+1],by1)),0.0f);
    float inter=__fmul_rn(iw,ih);
    float iou=__fdiv_rn(inter, __fsub_rn(__fadd_rn(areaS[j],ai),inter));
    if (iou>0.7f) word |= (1ULL<<(j-jbase));
  }
  maskT[(size_t)w*NP + i]=word;
}

// chunk-64 gather NMS with early exit at rank>=1000 (exact: kept boxes with
// rank>=1000 are dropped by the reference scatter, and cannot affect earlier ones).
__global__ void __launch_bounds__(64) k_nms(unsigned* ws32){
  const unsigned long long* maskT = (const unsigned long long*)(ws32+MASKO);
  const unsigned long long* validw = (const unsigned long long*)(ws32+VALSB);
  int lane = threadIdx.x;
  __shared__ unsigned long long Kb[NW];   // kept word per finished chunk
  __shared__ unsigned long long Vb[NW];   // valid words
  if (lane < NCH) Vb[lane] = validw[lane];
  __syncthreads();
  unsigned long long lower = (lane==0)?0ULL:(~0ULL >> (64-lane));
  int rank=0;
  for (int c=0;c<NCH;c++){
    int q = (c<<6) + lane;
    size_t qc = (q < NSEL)? (size_t)q : (size_t)(NSEL-1);  // clamped lanes have valid=0, never kept
    unsigned long long sup=0ULL;
    #pragma unroll 8
    for (int w=0; w<c; ++w)
      sup |= maskT[(size_t)w*NP + qc] & Kb[w];
    unsigned long long intra = maskT[(size_t)c*NP + qc];
    unsigned long long valc  = Vb[c];
    bool al = ((valc>>lane)&1ULL) && (sup==0ULL);
    unsigned long long nd = intra & lower;   // smaller-index in-chunk suppressors
    unsigned long long kept = __ballot(al);
    for (int it=0; it<96; ++it){
      bool s2 = (kept & nd) != 0ULL;
      unsigned long long nk = __ballot(al && !s2);
      if (nk==kept) break;
      kept = nk;
    }
    if ((kept>>lane)&1ULL){
      int pos = rank + (int)__popcll(kept & lower);
      if (pos < K_TOP) ws32[ORDERED+pos] = (unsigned)q;
    }
    rank += (int)__popcll(kept);
    if (rank >= K_TOP) break;
    if (lane==0) Kb[c] = kept;
    __syncthreads();
  }
  if (lane==0) ws32[KEPT] = (unsigned)((rank>K_TOP)?K_TOP:rank);
}

__global__ void k_out(const unsigned* __restrict__ ws32, float* __restrict__ out){
  int r = blockIdx.x*blockDim.x + threadIdx.x;
  if (r>=K_TOP) return;
  unsigned cnt = ws32[KEPT];
  float4 v = make_float4(0.f,0.f,0.f,0.f);
  if (r < (int)cnt){
    unsigned i = ws32[ORDERED + r];
    unsigned cp = ws32[SORTCP + i];
    int l = cp/1000, j = cp - l*1000;
    int s = (l<<10)|j;
    const float* b = (const float*)(ws32+BOXA) + 4*s;
    v = make_float4(b[0],b[1],b[2],b[3]);
  }
  ((float4*)out)[r] = v;
}

extern "C" void kernel_launch(void* const* d_in, const int* in_sizes, int n_in,
                              void* d_out, int out_size, void* d_ws, size_t ws_size,
                              hipStream_t stream){
  const float* obj     = (const float*)d_in[0];
  const float* deltas  = (const float*)d_in[1];
  const float* anchors = (const float*)d_in[2];
  unsigned* ws32 = (unsigned*)d_ws;
  float* out = (float*)d_out;
  (void)in_sizes; (void)n_in; (void)out_size; (void)ws_size;

  hipLaunchKernelGGL(k_init,     dim3(128),      dim3(256), 0, stream, ws32);
  hipLaunchKernelGGL(k_hist,     dim3(104,5),    dim3(256), 0, stream, obj, ws32, 1);
  hipLaunchKernelGGL(k_scan,     dim3(5),        dim3(256), 0, stream, ws32, 1);
  hipLaunchKernelGGL(k_hist,     dim3(104,5),    dim3(256), 0, stream, obj, ws32, 2);
  hipLaunchKernelGGL(k_scan,     dim3(5),        dim3(256), 0, stream, ws32, 2);
  hipLaunchKernelGGL(k_hist,     dim3(104,5),    dim3(256), 0, stream, obj, ws32, 3);
  hipLaunchKernelGGL(k_scan,     dim3(5),        dim3(256), 0, stream, ws32, 3);
  hipLaunchKernelGGL(k_select,   dim3(512),      dim3(256), 0, stream, obj, ws32);
  hipLaunchKernelGGL(k_eqfix,    dim3(5),        dim3(1024),0, stream, ws32);
  hipLaunchKernelGGL(k_sortlvl,  dim3(5),        dim3(512), 0, stream, obj, ws32);
  hipLaunchKernelGGL(k_decode,   dim3(5),        dim3(1024),0, stream, obj, deltas, anchors, ws32);
  hipLaunchKernelGGL(k_part,     dim3(5),        dim3(1024),0, stream, ws32);
  hipLaunchKernelGGL(k_merge,    dim3(5),        dim3(1024),0, stream, ws32);
  hipLaunchKernelGGL(k_prep,     dim3(20),       dim3(256), 0, stream, ws32);
  hipLaunchKernelGGL(k_mask,     dim3(79,79),    dim3(64),  0, stream, ws32);
  hipLaunchKernelGGL(k_nms,      dim3(1),        dim3(64),  0, stream, ws32);
  hipLaunchKernelGGL(k_out,      dim3(4),        dim3(256), 0, stream, ws32, out);
}